// Round 2
// baseline (433.605 us; speedup 1.0000x reference)
//
#include <hip/hip_runtime.h>
#include <stdint.h>

typedef unsigned short u16;
typedef __bf16 bf16x8 __attribute__((ext_vector_type(8)));
typedef float f32x4 __attribute__((ext_vector_type(4)));

#define SCALE_F 0.014731391274719742f   // 1/sqrt(512*9)

// ---- workspace layout (bytes) ----
#define S_OFF   0u          // s[8][512] f32          (16 KB)
#define DM_OFF  16384u      // demod[8][512] f32      (16 KB)
#define WSQ_OFF 32768u      // wsq[512][512] f32      (1 MB)
#define WM_OFF  1081344u    // Wm bf16 [8][512][4608], k' = tap*512+i   (37.75 MB)
#define XS_OFF  38830080u   // Xs bf16 [8][66][66][512]  (35.68 MB), channel-innermost
#define WS_NEED 74514432u

__device__ __forceinline__ u16 f2bf(float f) {
  union { float f; uint32_t u; } c; c.f = f;
  return (u16)((c.u + 0x7FFFu + ((c.u >> 16) & 1u)) >> 16);  // RNE
}

__device__ __forceinline__ void gload16(const void* g, void* l) {
  __builtin_amdgcn_global_load_lds(
      (const __attribute__((address_space(1))) uint32_t*)g,
      (__attribute__((address_space(3))) uint32_t*)l, 16, 0, 0);
}

// K1: s[n][c] = style[n] . style_w[c] + style_b[c]   (grid 16x256)
__global__ void k_style(const float* __restrict__ style, const float* __restrict__ sw,
                        const float* __restrict__ sb, float* __restrict__ s) {
  int t = blockIdx.x * 256 + threadIdx.x;          // 4096
  int n = t >> 9, c = t & 511;
  const float4* wr = (const float4*)(sw + (size_t)c * 512);
  const float4* st = (const float4*)(style + (size_t)n * 512);
  float acc = 0.f;
  #pragma unroll 4
  for (int d = 0; d < 128; ++d) {
    float4 a = st[d], b = wr[d];
    acc += a.x * b.x + a.y * b.y + a.z * b.z + a.w * b.w;
  }
  s[t] = acc + sb[c];
}

// K2: wsq[o*512+i] = sum_r weight[(o*512+i)*9+r]^2   (grid 1024x256)
__global__ void k_wsq(const float* __restrict__ w, float* __restrict__ wsq) {
  int t = blockIdx.x * 256 + threadIdx.x;          // 262144
  const float* p = w + (size_t)t * 9;
  float a = 0.f;
  #pragma unroll
  for (int r = 0; r < 9; ++r) a += p[r] * p[r];
  wsq[t] = a;
}

// K3: demod[n][o] = rsqrt(1/4608 * sum_i s[n,i]^2 * wsq[o,i] + 1e-8)  (grid 16x256)
__global__ void k_demod(const float* __restrict__ s, const float* __restrict__ wsq,
                        float* __restrict__ dm) {
  int t = blockIdx.x * 256 + threadIdx.x;          // 4096
  int n = t >> 9, o = t & 511;
  const float4* sp = (const float4*)(s + (size_t)n * 512);
  const float4* wp = (const float4*)(wsq + (size_t)o * 512);
  float acc = 0.f;
  #pragma unroll 4
  for (int d = 0; d < 128; ++d) {
    float4 a = sp[d], b = wp[d];
    acc += a.x * a.x * b.x + a.y * a.y * b.y + a.z * a.z * b.z + a.w * a.w * b.w;
  }
  dm[t] = rsqrtf((1.0f / 4608.0f) * acc + 1e-8f);
}

// K4: Wm[(n*512+o)*4608 + r*512 + i] = bf16(weight[(o*512+i)*9+r]*SCALE*s[n,i]*dm[n,o])
__global__ void k_wmod(const float* __restrict__ w, const float* __restrict__ s,
                       const float* __restrict__ dm, u16* __restrict__ wm) {
  uint32_t t = blockIdx.x * 256 + threadIdx.x;     // 18,874,368
  uint32_t k = t % 4608u;
  uint32_t no = t / 4608u;                          // n*512+o
  uint32_t o = no & 511u, n = no >> 9;
  uint32_t r = k >> 9, i = k & 511u;
  float v = w[((size_t)o * 512u + i) * 9u + r] * SCALE_F * s[n * 512u + i] * dm[no];
  wm[t] = f2bf(v);
}

// K5a: zero all of Xs (border padding must be 0; ws is poisoned 0xAA each call)
__global__ void k_zero(uint4* __restrict__ p) {
  uint32_t t = blockIdx.x * 256u + threadIdx.x;     // 2,230,272 x 16B
  uint4 z = {0u, 0u, 0u, 0u};
  p[t] = z;
}

// K5b: Xs[n][hs+1][w+1][i] = bf16(x[n][i][hs][w]) — transpose to channel-innermost
// One block per (n, hs): [512 i][64 w] f32 in, [64 w][512 i] bf16 out, via LDS.
__global__ __launch_bounds__(256) void k_xpose(const float* __restrict__ x,
                                               u16* __restrict__ xs) {
  __shared__ u16 tile[64][520];   // [w][i], +8 pad: rows 1040B (16B-aligned, bank offset 4)
  uint32_t b = blockIdx.x, n = b >> 6, hs = b & 63u;
  uint32_t t = threadIdx.x;
  const float* xr = x + ((size_t)n * 512u * 64u + hs) * 64u;   // + i*4096 + w
  #pragma unroll 4
  for (uint32_t p = 0; p < 32u; ++p) {
    uint32_t idx = p * 256u + t;
    uint32_t i = idx >> 4, w4 = (idx & 15u) * 4u;
    float4 v = *(const float4*)(xr + (size_t)i * 4096u + w4);
    tile[w4 + 0u][i] = f2bf(v.x);
    tile[w4 + 1u][i] = f2bf(v.y);
    tile[w4 + 2u][i] = f2bf(v.z);
    tile[w4 + 3u][i] = f2bf(v.w);
  }
  __syncthreads();
  u16* orow = xs + (((size_t)n * 66u + hs + 1u) * 66u + 1u) * 512u;  // hp=hs+1, wp=w+1
  #pragma unroll 4
  for (uint32_t p = 0; p < 16u; ++p) {
    uint32_t idx = p * 256u + t;
    uint32_t w = idx >> 6, i8 = (idx & 63u) * 8u;
    *(bf16x8*)(orow + (size_t)w * 512u + i8) = *(const bf16x8*)(&tile[w][i8]);
  }
}

// Conv as implicit GEMM per sample, SWAPPED operands: C[p][o] = sum_k X[p][k]*W[k][o]
// (M = spatial p, N = out-channel o). Both LDS tiles are row-major [row][64 k]
// with the G4 chunk-XOR swizzle; both fragments are plain ds_read_b128.
// 128x128 tile, BK=64, 4 waves, mfma_f32_16x16x32_bf16, double-buffered LDS.
__global__ __launch_bounds__(256, 2) void k_conv(
    const u16* __restrict__ Wm, const u16* __restrict__ Xs, float* __restrict__ out)
{
  __shared__ u16 As[2][8192];   // [128 p][64 i] rows 128B, chunk-XOR swizzled
  __shared__ u16 Bs[2][8192];   // [128 o][64 k] rows 128B, chunk-XOR swizzled

  const uint32_t bid = blockIdx.x;
  const uint32_t swz = (bid & 7u) * 128u + (bid >> 3);   // XCD swizzle, bijective (1024%8==0)
  const uint32_t n = swz >> 7, ot = (swz >> 5) & 3u, pt = swz & 31u;

  const uint32_t tid = threadIdx.x;
  const uint32_t wid = tid >> 6, lane = tid & 63u;
  const uint32_t l16 = lane & 15u, lg = lane >> 4;
  const uint32_t wr = wid >> 1, wc = wid & 1u;   // wr: p-half (M), wc: o-half (N)
  const uint32_t rl = lane >> 3, cl = lane & 7u; // staging: row-in-8, 16B chunk

  const u16* wmn = Wm + (size_t)(n * 512u + ot * 128u) * 4608u;
  const u16* xsn = Xs + (size_t)n * 66u * 66u * 512u;
  const uint32_t h0 = pt * 2u;

  f32x4 acc[4][4];
  f32x4 zero = {0.f, 0.f, 0.f, 0.f};
  #pragma unroll
  for (int m = 0; m < 4; ++m)
    #pragma unroll
    for (int nn = 0; nn < 4; ++nn) acc[m][nn] = zero;

  auto stage = [&](uint32_t bf, uint32_t t) {
    const uint32_t r = t >> 3, i0 = (t & 7u) << 6;     // tap r, i-block
    const uint32_t kh = r / 3u, kw = r % 3u;
    #pragma unroll
    for (uint32_t s4 = 0; s4 < 4u; ++s4) {
      const uint32_t L = wid * 4u + s4;                // load index 0..15, 1KB each
      const uint32_t row = L * 8u + rl;                // p_local (A) / o_local (B)
      const uint32_t csrc = cl ^ (row & 7u);           // pre-swizzled SOURCE, linear dest
      // A: X rows — p=(h,w): hp = h0+(row>>6)+kh, wp = (row&63)+kw, i-run contiguous
      const uint32_t hp = h0 + (row >> 6) + kh, wp = (row & 63u) + kw;
      gload16(xsn + ((size_t)hp * 66u + wp) * 512u + i0 + csrc * 8u, &As[bf][L * 512u]);
      // B: Wm rows — o: k' = r*512 + i contiguous
      gload16(wmn + (size_t)row * 4608u + r * 512u + i0 + csrc * 8u, &Bs[bf][L * 512u]);
    }
  };

  auto compute = [&](uint32_t bf) {
    const u16* as = &As[bf][0];
    const u16* bs = &Bs[bf][0];
    #pragma unroll
    for (uint32_t kk = 0; kk < 2u; ++kk) {
      bf16x8 a[4], b[4];
      #pragma unroll
      for (uint32_t m = 0; m < 4u; ++m) {
        const uint32_t row = wr * 64u + m * 16u + l16;
        const uint32_t c = (kk * 4u + lg) ^ (row & 7u);   // undo staging swizzle
        a[m] = *(const bf16x8*)(as + row * 64u + c * 8u); // ds_read_b128
      }
      #pragma unroll
      for (uint32_t nn = 0; nn < 4u; ++nn) {
        const uint32_t row = wc * 64u + nn * 16u + l16;
        const uint32_t c = (kk * 4u + lg) ^ (row & 7u);
        b[nn] = *(const bf16x8*)(bs + row * 64u + c * 8u);
      }
      #pragma unroll
      for (uint32_t m = 0; m < 4u; ++m)
        #pragma unroll
        for (uint32_t nn = 0; nn < 4u; ++nn)
          acc[m][nn] = __builtin_amdgcn_mfma_f32_16x16x32_bf16(a[m], b[nn], acc[m][nn], 0, 0, 0);
    }
  };

  stage(0u, 0u);
  __syncthreads();
  uint32_t cur = 0u;
  for (uint32_t t = 0; t < 72u; ++t) {
    if (t < 71u) stage(cur ^ 1u, t + 1u);   // prefetch overlaps compute; drained at barrier
    compute(cur);
    __syncthreads();                         // compiler emits vmcnt(0) lgkmcnt(0) + s_barrier
    cur ^= 1u;
  }

  // C[p][o]: lane reg q -> p = pbase + m*16 + lg*4 + q (contiguous!), o = obase + nn*16 + l16
  float* op = out + ((size_t)n * 512u + ot * 128u + wc * 64u) * 4096u + pt * 128u + wr * 64u;
  #pragma unroll
  for (uint32_t m = 0; m < 4u; ++m)
    #pragma unroll
    for (uint32_t nn = 0; nn < 4u; ++nn)
      *(f32x4*)(op + (size_t)(nn * 16u + l16) * 4096u + m * 16u + lg * 4u) = acc[m][nn];
}

extern "C" void kernel_launch(void* const* d_in, const int* in_sizes, int n_in,
                              void* d_out, int out_size, void* d_ws, size_t ws_size,
                              hipStream_t stream) {
  const float* x       = (const float*)d_in[0];
  const float* style   = (const float*)d_in[1];
  const float* weight  = (const float*)d_in[2];
  const float* style_w = (const float*)d_in[3];
  const float* style_b = (const float*)d_in[4];
  float* out = (float*)d_out;

  if (ws_size < (size_t)WS_NEED) return;  // loud failure (output stays wrong)

  char* ws = (char*)d_ws;
  float* s   = (float*)(ws + S_OFF);
  float* dm  = (float*)(ws + DM_OFF);
  float* wsq = (float*)(ws + WSQ_OFF);
  u16*   wm  = (u16*)(ws + WM_OFF);
  u16*   xs  = (u16*)(ws + XS_OFF);

  hipLaunchKernelGGL(k_style, dim3(16),    dim3(256), 0, stream, style, style_w, style_b, s);
  hipLaunchKernelGGL(k_wsq,   dim3(1024),  dim3(256), 0, stream, weight, wsq);
  hipLaunchKernelGGL(k_demod, dim3(16),    dim3(256), 0, stream, s, wsq, dm);
  hipLaunchKernelGGL(k_wmod,  dim3(73728), dim3(256), 0, stream, weight, s, dm, wm);
  hipLaunchKernelGGL(k_zero,  dim3(8712),  dim3(256), 0, stream, (uint4*)xs);
  hipLaunchKernelGGL(k_xpose, dim3(512),   dim3(256), 0, stream, x, xs);
  hipLaunchKernelGGL(k_conv,  dim3(1024),  dim3(256), 0, stream, wm, xs, out);
}

// Round 4
// 328.279 us; speedup vs baseline: 1.3208x; 1.3208x over previous
//
#include <hip/hip_runtime.h>
#include <stdint.h>

typedef unsigned short u16;
typedef __bf16 bf16x8 __attribute__((ext_vector_type(8)));
typedef float f32x4 __attribute__((ext_vector_type(4)));

#define SCALE_F 0.014731391274719742f   // 1/sqrt(512*9)

// ---- workspace layout (bytes) ----
#define S_OFF   0u          // s[8][512] f32          (16 KB)
#define DM_OFF  16384u      // demod[8][512] f32      (16 KB)
#define WSQ_OFF 32768u      // wsq[512][512] f32      (1 MB)
#define WM_OFF  1081344u    // Wm bf16 [8][512][4608], k' = tap*512+i   (37.75 MB)
#define XS_OFF  38830080u   // Xs bf16 [8][66][66][512]  (35.68 MB), channel-innermost
#define WS_NEED 74514432u

__device__ __forceinline__ u16 f2bf(float f) {
  union { float f; uint32_t u; } c; c.f = f;
  return (u16)((c.u + 0x7FFFu + ((c.u >> 16) & 1u)) >> 16);  // RNE
}

__device__ __forceinline__ void gload16(const void* g, void* l) {
  __builtin_amdgcn_global_load_lds(
      (const __attribute__((address_space(1))) uint32_t*)g,
      (__attribute__((address_space(3))) uint32_t*)l, 16, 0, 0);
}

// K1: s[n][c] = style[n] . style_w[c] + style_b[c]   (grid 16x256)
__global__ void k_style(const float* __restrict__ style, const float* __restrict__ sw,
                        const float* __restrict__ sb, float* __restrict__ s) {
  int t = blockIdx.x * 256 + threadIdx.x;          // 4096
  int n = t >> 9, c = t & 511;
  const float4* wr = (const float4*)(sw + (size_t)c * 512);
  const float4* st = (const float4*)(style + (size_t)n * 512);
  float acc = 0.f;
  #pragma unroll 4
  for (int d = 0; d < 128; ++d) {
    float4 a = st[d], b = wr[d];
    acc += a.x * b.x + a.y * b.y + a.z * b.z + a.w * b.w;
  }
  s[t] = acc + sb[c];
}

// K2: wsq[o*512+i] = sum_r weight[(o*512+i)*9+r]^2   (grid 1024x256)
__global__ void k_wsq(const float* __restrict__ w, float* __restrict__ wsq) {
  int t = blockIdx.x * 256 + threadIdx.x;          // 262144
  const float* p = w + (size_t)t * 9;
  float a = 0.f;
  #pragma unroll
  for (int r = 0; r < 9; ++r) a += p[r] * p[r];
  wsq[t] = a;
}

// K3: demod[n][o] = rsqrt(1/4608 * sum_i s[n,i]^2 * wsq[o,i] + 1e-8)  (grid 16x256)
__global__ void k_demod(const float* __restrict__ s, const float* __restrict__ wsq,
                        float* __restrict__ dm) {
  int t = blockIdx.x * 256 + threadIdx.x;          // 4096
  int n = t >> 9, o = t & 511;
  const float4* sp = (const float4*)(s + (size_t)n * 512);
  const float4* wp = (const float4*)(wsq + (size_t)o * 512);
  float acc = 0.f;
  #pragma unroll 4
  for (int d = 0; d < 128; ++d) {
    float4 a = sp[d], b = wp[d];
    acc += a.x * a.x * b.x + a.y * a.y * b.y + a.z * a.z * b.z + a.w * a.w * b.w;
  }
  dm[t] = rsqrtf((1.0f / 4608.0f) * acc + 1e-8f);
}

// K4: one block per o. LDS-transpose weight[o][i][r] -> k'=r*512+i order, then
// emit all 8 samples. Coalesced global reads AND writes; stride-9 LDS reads
// are bank-coprime (gcd(9,32)=1).
__global__ __launch_bounds__(256) void k_wmod2(
    const float* __restrict__ w, const float* __restrict__ s,
    const float* __restrict__ dm, u16* __restrict__ wm) {
  __shared__ float wlds[4608];
  __shared__ float slds[4096];
  const uint32_t o = blockIdx.x, t = threadIdx.x;
  #pragma unroll
  for (uint32_t c = 0; c < 18u; ++c)
    wlds[c * 256u + t] = w[(size_t)o * 4608u + c * 256u + t] * SCALE_F;
  #pragma unroll
  for (uint32_t c = 0; c < 16u; ++c)
    slds[c * 256u + t] = s[c * 256u + t];
  float dmv[8];
  #pragma unroll
  for (uint32_t nn = 0; nn < 8u; ++nn) dmv[nn] = dm[nn * 512u + o];
  __syncthreads();
  #pragma unroll 2
  for (uint32_t c = 0; c < 18u; ++c) {
    uint32_t idx = c * 256u + t;
    uint32_t i = idx & 511u, r = idx >> 9;
    float wv = wlds[i * 9u + r];
    #pragma unroll
    for (uint32_t nn = 0; nn < 8u; ++nn)
      wm[((size_t)nn * 512u + o) * 4608u + idx] = f2bf(wv * slds[nn * 512u + i] * dmv[nn]);
  }
}

// K5a: zero all of Xs (border padding must be 0; ws is poisoned 0xAA each call)
__global__ void k_zero(uint4* __restrict__ p) {
  uint32_t t = blockIdx.x * 256u + threadIdx.x;     // 2,230,272 x 16B
  uint4 z = {0u, 0u, 0u, 0u};
  p[t] = z;
}

// K5b: Xs[n][hs+1][w+1][i] = bf16(x[n][i][hs][w]) — transpose to channel-innermost
__global__ __launch_bounds__(256) void k_xpose(const float* __restrict__ x,
                                               u16* __restrict__ xs) {
  __shared__ u16 tile[64][520];
  uint32_t b = blockIdx.x, n = b >> 6, hs = b & 63u;
  uint32_t t = threadIdx.x;
  const float* xr = x + ((size_t)n * 512u * 64u + hs) * 64u;   // + i*4096 + w
  #pragma unroll 4
  for (uint32_t p = 0; p < 32u; ++p) {
    uint32_t idx = p * 256u + t;
    uint32_t i = idx >> 4, w4 = (idx & 15u) * 4u;
    float4 v = *(const float4*)(xr + (size_t)i * 4096u + w4);
    tile[w4 + 0u][i] = f2bf(v.x);
    tile[w4 + 1u][i] = f2bf(v.y);
    tile[w4 + 2u][i] = f2bf(v.z);
    tile[w4 + 3u][i] = f2bf(v.w);
  }
  __syncthreads();
  u16* orow = xs + (((size_t)n * 66u + hs + 1u) * 66u + 1u) * 512u;  // hp=hs+1, wp=w+1
  #pragma unroll 4
  for (uint32_t p = 0; p < 16u; ++p) {
    uint32_t idx = p * 256u + t;
    uint32_t w = idx >> 6, i8 = (idx & 63u) * 8u;
    *(bf16x8*)(orow + (size_t)w * 512u + i8) = *(const bf16x8*)(&tile[w][i8]);
  }
}

// ---------------------------------------------------------------------------
// K6: conv as implicit GEMM, 8-phase schedule (T3+T4+T5), 256x256 tile, BK=64.
// C[p][o] = sum_k X[p][k] * W[k][o].  8 waves = 2(M) x 4(N); wave owns 128x64.
// LDS 128 KB dynamic: A[2][256][64] + B[2][256][64] bf16, chunk-XOR swizzled.
// Half-tiles (128 rows x 64 k = 2 gloads/thread), order [A0,A1,B0,B1].
// Lead C=7: phase P issues half P+7. vmcnt(6) at each tile's last phase
// publishes the NEXT tile (3 half-tiles stay in flight across barriers).
// Quadrants: p0=(m0-3,n0-1) p1=(m4-7,n0-1) p2=(m0-3,n2-3) p3=(m4-7,n2-3).
// ds-reads: p0 = all 16 a-frags + b01 (20), p1 = b23 (4), p2/p3 = 0.
// Race-freedom: A-halves fully read-drained at p0's lgkmcnt(0) (published by
// p0 barrier2) before their p1/p2 overwrite; B-halves drained at p1 before p3.
// ---------------------------------------------------------------------------
__global__ __launch_bounds__(512, 2) void k_conv8(
    const u16* __restrict__ Wm, const u16* __restrict__ Xs, float* __restrict__ out)
{
  extern __shared__ u16 smem[];           // A: [0, 32768), B: [32768, 65536) u16
  u16* As = smem;
  u16* Bs = smem + 32768;

  const uint32_t bid = blockIdx.x;
  const uint32_t swz = (bid & 7u) * 32u + (bid >> 3);   // XCD swizzle, 256%8==0
  const uint32_t n = swz >> 5, ot = (swz >> 4) & 1u, pt = swz & 15u;

  const uint32_t tid = threadIdx.x;
  const uint32_t wid = tid >> 6, lane = tid & 63u;
  const uint32_t l16 = lane & 15u, lg = lane >> 4;
  const uint32_t wm = wid >> 2, wn = wid & 3u;   // wave: M-half (128 p), N-quarter (64 o)

  const u16* wmn = Wm + (size_t)n * 512u * 4608u;
  const u16* xsn = Xs + (size_t)n * 66u * 66u * 512u;

  f32x4 acc[8][4];
  f32x4 zero = {0.f, 0.f, 0.f, 0.f};
  #pragma unroll
  for (int m = 0; m < 8; ++m)
    #pragma unroll
    for (int nn = 0; nn < 4; ++nn) acc[m][nn] = zero;

  // stage one half-tile h (global index 0..287): tile Tt = h>>2, q = h&3
  // q: 0 = A rows 0-127, 1 = A rows 128-255, 2 = B rows 0-127, 3 = B rows 128-255
  auto stage = [&](uint32_t h) {
    if (h >= 288u) return;                      // uniform guard
    const uint32_t Tt = h >> 2, q = h & 3u;
    const uint32_t buf = Tt & 1u;
    const uint32_t r = Tt >> 3, i0 = (Tt & 7u) << 6;   // tap r, i-block
    const uint32_t kh = r / 3u, kw = r % 3u;
    const uint32_t half = q & 1u;
    #pragma unroll
    for (uint32_t j = 0; j < 2u; ++j) {
      const uint32_t sl = tid + j * 512u;       // slot 0..1023 (row*8 + chunk)
      const uint32_t row = sl >> 3, cl = sl & 7u;
      const uint32_t csrc = cl ^ (row & 7u);    // pre-swizzled SOURCE, linear dest
      u16* dst;
      const u16* src;
      if (q < 2u) {                             // A: X rows (spatial p)
        const uint32_t R = half * 128u + row;   // block M row 0..255
        const uint32_t hp = pt * 4u + (R >> 6) + kh, wp = (R & 63u) + kw;
        src = xsn + ((size_t)hp * 66u + wp) * 512u + i0 + csrc * 8u;
        dst = As + buf * 16384u + half * 8192u + (wid * 64u + j * 512u) * 8u;
      } else {                                  // B: Wm rows (out-channel o)
        const uint32_t o = ot * 256u + half * 128u + row;
        src = wmn + (size_t)o * 4608u + r * 512u + i0 + csrc * 8u;
        dst = Bs + buf * 16384u + half * 8192u + (wid * 64u + j * 512u) * 8u;
      }
      gload16(src, dst);
    }
  };

  // prologue: issue halves 0..6 (tile0 complete + 3 ahead), publish tile 0
  for (uint32_t h = 0; h < 7u; ++h) stage(h);
  asm volatile("s_waitcnt vmcnt(6)" ::: "memory");
  __builtin_amdgcn_s_barrier();

  bf16x8 a[8][2], b01[2][2], b23[2][2];

  for (uint32_t T = 0; T < 72u; ++T) {
    const uint32_t buf = T & 1u;
    const u16* Ab = As + buf * 16384u;
    const u16* Bb = Bs + buf * 16384u;
    const uint32_t P = T * 4u;

    // ---- phase 0: read all A frags + b01; MFMA quad (m0-3, n0-1) ----
    #pragma unroll
    for (uint32_t m = 0; m < 8u; ++m) {
      const uint32_t row = wm * 128u + m * 16u + l16;
      #pragma unroll
      for (uint32_t k = 0; k < 2u; ++k) {
        const uint32_t c = (k * 4u + lg) ^ (row & 7u);
        a[m][k] = *(const bf16x8*)(Ab + row * 64u + c * 8u);
      }
    }
    #pragma unroll
    for (uint32_t nn = 0; nn < 2u; ++nn) {
      const uint32_t row = wn * 64u + nn * 16u + l16;
      #pragma unroll
      for (uint32_t k = 0; k < 2u; ++k) {
        const uint32_t c = (k * 4u + lg) ^ (row & 7u);
        b01[nn][k] = *(const bf16x8*)(Bb + row * 64u + c * 8u);
      }
    }
    stage(P + 7u);
    __builtin_amdgcn_s_barrier();
    asm volatile("s_waitcnt lgkmcnt(0)" ::: "memory");
    __builtin_amdgcn_sched_barrier(0);
    __builtin_amdgcn_s_setprio(1);
    #pragma unroll
    for (uint32_t m = 0; m < 4u; ++m)
      #pragma unroll
      for (uint32_t nn = 0; nn < 2u; ++nn)
        #pragma unroll
        for (uint32_t k = 0; k < 2u; ++k)
          acc[m][nn] = __builtin_amdgcn_mfma_f32_16x16x32_bf16(a[m][k], b01[nn][k], acc[m][nn], 0, 0, 0);
    __builtin_amdgcn_s_setprio(0);
    __builtin_amdgcn_s_barrier();

    // ---- phase 1: read b23; MFMA quad (m4-7, n0-1) ----
    #pragma unroll
    for (uint32_t nn = 0; nn < 2u; ++nn) {
      const uint32_t row = wn * 64u + (nn + 2u) * 16u + l16;
      #pragma unroll
      for (uint32_t k = 0; k < 2u; ++k) {
        const uint32_t c = (k * 4u + lg) ^ (row & 7u);
        b23[nn][k] = *(const bf16x8*)(Bb + row * 64u + c * 8u);
      }
    }
    stage(P + 8u);
    __builtin_amdgcn_s_barrier();
    asm volatile("s_waitcnt lgkmcnt(0)" ::: "memory");
    __builtin_amdgcn_sched_barrier(0);
    __builtin_amdgcn_s_setprio(1);
    #pragma unroll
    for (uint32_t m = 0; m < 4u; ++m)
      #pragma unroll
      for (uint32_t nn = 0; nn < 2u; ++nn)
        #pragma unroll
        for (uint32_t k = 0; k < 2u; ++k)
          acc[m + 4u][nn] = __builtin_amdgcn_mfma_f32_16x16x32_bf16(a[m + 4u][k], b01[nn][k], acc[m + 4u][nn], 0, 0, 0);
    __builtin_amdgcn_s_setprio(0);
    __builtin_amdgcn_s_barrier();

    // ---- phase 2: MFMA quad (m0-3, n2-3) ----
    stage(P + 9u);
    __builtin_amdgcn_s_barrier();
    __builtin_amdgcn_s_setprio(1);
    #pragma unroll
    for (uint32_t m = 0; m < 4u; ++m)
      #pragma unroll
      for (uint32_t nn = 0; nn < 2u; ++nn)
        #pragma unroll
        for (uint32_t k = 0; k < 2u; ++k)
          acc[m][nn + 2u] = __builtin_amdgcn_mfma_f32_16x16x32_bf16(a[m][k], b23[nn][k], acc[m][nn + 2u], 0, 0, 0);
    __builtin_amdgcn_s_setprio(0);
    __builtin_amdgcn_s_barrier();

    // ---- phase 3: MFMA quad (m4-7, n2-3); vmcnt publishes tile T+1 ----
    stage(P + 10u);
    __builtin_amdgcn_s_barrier();
    __builtin_amdgcn_s_setprio(1);
    #pragma unroll
    for (uint32_t m = 0; m < 4u; ++m)
      #pragma unroll
      for (uint32_t nn = 0; nn < 2u; ++nn)
        #pragma unroll
        for (uint32_t k = 0; k < 2u; ++k)
          acc[m + 4u][nn + 2u] = __builtin_amdgcn_mfma_f32_16x16x32_bf16(a[m + 4u][k], b23[nn][k], acc[m + 4u][nn + 2u], 0, 0, 0);
    __builtin_amdgcn_s_setprio(0);
    if (T < 70u) {
      asm volatile("s_waitcnt vmcnt(6)" ::: "memory");
    } else if (T == 70u) {
      asm volatile("s_waitcnt vmcnt(0)" ::: "memory");
    }
    __builtin_amdgcn_s_barrier();
  }

  // C[p][o]: lane reg q -> p = pbase + m*16 + lg*4 + q (contiguous), o = obase + nn*16 + l16
  float* op = out + ((size_t)n * 512u + ot * 256u + wn * 64u) * 4096u + pt * 256u + wm * 128u;
  #pragma unroll
  for (uint32_t m = 0; m < 8u; ++m)
    #pragma unroll
    for (uint32_t nn = 0; nn < 4u; ++nn)
      *(f32x4*)(op + (size_t)(nn * 16u + l16) * 4096u + m * 16u + lg * 4u) = acc[m][nn];
}

extern "C" void kernel_launch(void* const* d_in, const int* in_sizes, int n_in,
                              void* d_out, int out_size, void* d_ws, size_t ws_size,
                              hipStream_t stream) {
  const float* x       = (const float*)d_in[0];
  const float* style   = (const float*)d_in[1];
  const float* weight  = (const float*)d_in[2];
  const float* style_w = (const float*)d_in[3];
  const float* style_b = (const float*)d_in[4];
  float* out = (float*)d_out;

  if (ws_size < (size_t)WS_NEED) return;  // loud failure (output stays wrong)

  char* ws = (char*)d_ws;
  float* s   = (float*)(ws + S_OFF);
  float* dm  = (float*)(ws + DM_OFF);
  float* wsq = (float*)(ws + WSQ_OFF);
  u16*   wm  = (u16*)(ws + WM_OFF);
  u16*   xs  = (u16*)(ws + XS_OFF);

  (void)hipFuncSetAttribute((const void*)k_conv8,
                            hipFuncAttributeMaxDynamicSharedMemorySize, 131072);

  hipLaunchKernelGGL(k_style, dim3(16),    dim3(256), 0, stream, style, style_w, style_b, s);
  hipLaunchKernelGGL(k_wsq,   dim3(1024),  dim3(256), 0, stream, weight, wsq);
  hipLaunchKernelGGL(k_demod, dim3(16),    dim3(256), 0, stream, s, wsq, dm);
  hipLaunchKernelGGL(k_wmod2, dim3(512),   dim3(256), 0, stream, weight, s, dm, wm);
  hipLaunchKernelGGL(k_zero,  dim3(8712),  dim3(256), 0, stream, (uint4*)xs);
  hipLaunchKernelGGL(k_xpose, dim3(512),   dim3(256), 0, stream, x, xs);
  hipLaunchKernelGGL(k_conv8, dim3(256),   dim3(512), 131072, stream, wm, xs, out);
}

// Round 6
// 301.479 us; speedup vs baseline: 1.4383x; 1.0889x over previous
//
#include <hip/hip_runtime.h>
#include <stdint.h>

typedef unsigned short u16;
typedef __bf16 bf16x8 __attribute__((ext_vector_type(8)));
typedef float f32x4 __attribute__((ext_vector_type(4)));

#define SCALE_F 0.014731391274719742f   // 1/sqrt(512*9)

// ---- workspace layout (bytes) ----
#define S_OFF   0u          // s[8][512] f32          (16 KB)
#define WM_OFF  1081344u    // Wm bf16 [8][512][4608], k' = tap*512+i   (37.75 MB)
#define XS_OFF  38830080u   // Xs bf16 [8][66][66][512]  (35.68 MB), channel-innermost
#define WS_NEED 74514432u

__device__ __forceinline__ u16 f2bf(float f) {
  union { float f; uint32_t u; } c; c.f = f;
  return (u16)((c.u + 0x7FFFu + ((c.u >> 16) & 1u)) >> 16);  // RNE
}

__device__ __forceinline__ void gload16(const void* g, void* l) {
  __builtin_amdgcn_global_load_lds(
      (const __attribute__((address_space(1))) uint32_t*)g,
      (__attribute__((address_space(3))) uint32_t*)l, 16, 0, 0);
}

// K1: s[n][c] = style[n] . style_w[c] + style_b[c]   (grid 16x256)
__global__ void k_style(const float* __restrict__ style, const float* __restrict__ sw,
                        const float* __restrict__ sb, float* __restrict__ s) {
  int t = blockIdx.x * 256 + threadIdx.x;          // 4096
  int n = t >> 9, c = t & 511;
  const float4* wr = (const float4*)(sw + (size_t)c * 512);
  const float4* st = (const float4*)(style + (size_t)n * 512);
  float acc = 0.f;
  #pragma unroll 4
  for (int d = 0; d < 128; ++d) {
    float4 a = st[d], b = wr[d];
    acc += a.x * b.x + a.y * b.y + a.z * b.z + a.w * b.w;
  }
  s[t] = acc + sb[c];
}

// K2: one block per o. Loads w[o] (scaled) + s into LDS, computes demod[n][o]
// in-block (fuses old k_wsq+k_demod; no wsq/dm global round-trip), then emits
// Wm[(n*512+o)*4608 + r*512 + i] for all 8 n. Coalesced reads AND writes;
// stride-9 LDS reads bank-coprime (gcd(9,32)=1).
__global__ __launch_bounds__(256) void k_wmod3(
    const float* __restrict__ w, const float* __restrict__ s, u16* __restrict__ wm) {
  __shared__ float wlds[4608];
  __shared__ float slds[4096];
  __shared__ float red[8][4];
  __shared__ float dmv_sh[8];
  const uint32_t o = blockIdx.x, t = threadIdx.x;
  const uint32_t lane = t & 63u, wv = t >> 6;
  #pragma unroll
  for (uint32_t c = 0; c < 18u; ++c)
    wlds[c * 256u + t] = w[(size_t)o * 4608u + c * 256u + t] * SCALE_F;
  #pragma unroll
  for (uint32_t c = 0; c < 16u; ++c)
    slds[c * 256u + t] = s[c * 256u + t];
  __syncthreads();
  float part[8] = {0.f, 0.f, 0.f, 0.f, 0.f, 0.f, 0.f, 0.f};
  #pragma unroll
  for (uint32_t hh = 0; hh < 2u; ++hh) {        // i = hh*256 + t
    uint32_t i = hh * 256u + t;
    float q = 0.f;
    #pragma unroll
    for (uint32_t r = 0; r < 9u; ++r) { float a = wlds[i * 9u + r]; q += a * a; }
    #pragma unroll
    for (uint32_t nn = 0; nn < 8u; ++nn) {
      float sv = slds[nn * 512u + i];
      part[nn] += q * sv * sv;
    }
  }
  #pragma unroll
  for (uint32_t nn = 0; nn < 8u; ++nn) {
    float v = part[nn];
    #pragma unroll
    for (uint32_t off = 32u; off >= 1u; off >>= 1) v += __shfl_down(v, off);
    if (lane == 0u) red[nn][wv] = v;
  }
  __syncthreads();
  if (t < 8u)
    dmv_sh[t] = rsqrtf(red[t][0] + red[t][1] + red[t][2] + red[t][3] + 1e-8f);
  __syncthreads();
  float dmv[8];
  #pragma unroll
  for (uint32_t nn = 0; nn < 8u; ++nn) dmv[nn] = dmv_sh[nn];
  #pragma unroll 2
  for (uint32_t c = 0; c < 18u; ++c) {
    uint32_t idx = c * 256u + t;
    uint32_t i = idx & 511u, r = idx >> 9;
    float wvv = wlds[i * 9u + r];
    #pragma unroll
    for (uint32_t nn = 0; nn < 8u; ++nn)
      wm[((size_t)nn * 512u + o) * 4608u + idx] = f2bf(wvv * slds[nn * 512u + i] * dmv[nn]);
  }
}

// K3: zero ONLY the border of Xs (2.13 MB, not all 35.7 MB). Interior is
// fully overwritten by k_xpose. grid 520x256, one uint4 per thread.
__global__ void k_border(u16* __restrict__ xs) {
  uint32_t tg = blockIdx.x * 256u + threadIdx.x;   // 133,120
  uint32_t q = tg >> 6;        // border pixel id, 64 uint4 per pixel (512 u16)
  uint32_t r = tg & 63u;
  uint32_t n = q / 260u, b = q % 260u;
  uint32_t h, w;
  if (b < 66u)        { h = 0u;  w = b; }
  else if (b < 132u)  { h = 65u; w = b - 66u; }
  else { uint32_t c = b - 132u; h = 1u + (c >> 1); w = (c & 1u) * 65u; }
  uint4 z = {0u, 0u, 0u, 0u};
  *(uint4*)(xs + (((size_t)n * 66u + h) * 66u + w) * 512u + r * 8u) = z;
}

// K4: Xs[n][hs+1][w+1][i] = bf16(x[n][i][hs][w]) — NCHW f32 -> NHWC bf16.
// v2: each thread loads 8 float4 (8 i x 4 w), packs per-w into b128 LDS
// writes (bank-windows tile all 32 banks -> BW-bound, no 16-way conflicts).
__global__ __launch_bounds__(256) void k_xpose(const float* __restrict__ x,
                                               u16* __restrict__ xs) {
  __shared__ u16 tile[64][512];   // [w][i], 64 KB
  uint32_t b = blockIdx.x, n = b >> 6, hs = b & 63u;
  uint32_t t = threadIdx.x;
  const float* xr = x + ((size_t)n * 512u * 64u + hs) * 64u;   // + i*4096 + w
  uint32_t w4 = (t & 15u) * 4u;
  uint32_t ib = (t >> 4) * 8u;                                  // 0..120
  #pragma unroll
  for (uint32_t p = 0; p < 4u; ++p) {
    uint32_t i0 = p * 128u + ib;
    float4 v[8];
    #pragma unroll
    for (uint32_t j = 0; j < 8u; ++j)
      v[j] = *(const float4*)(xr + (size_t)(i0 + j) * 4096u + w4);
    #pragma unroll
    for (uint32_t k = 0; k < 4u; ++k) {
      union { u16 h[8]; uint4 q; } pk;
      #pragma unroll
      for (uint32_t j = 0; j < 8u; ++j) {
        float f = (k == 0u) ? v[j].x : (k == 1u) ? v[j].y : (k == 2u) ? v[j].z : v[j].w;
        pk.h[j] = f2bf(f);
      }
      *(uint4*)&tile[w4 + k][i0] = pk.q;        // ds_write_b128
    }
  }
  __syncthreads();
  u16* orow = xs + (((size_t)n * 66u + hs + 1u) * 66u + 1u) * 512u;  // hp=hs+1, wp=w+1
  #pragma unroll
  for (uint32_t p = 0; p < 16u; ++p) {
    uint32_t idx = p * 256u + t;
    uint32_t w = idx >> 6, i8 = (idx & 63u) * 8u;
    *(bf16x8*)(orow + (size_t)w * 512u + i8) = *(const bf16x8*)(&tile[w][i8]);
  }
}

// ---------------------------------------------------------------------------
// K5: conv implicit GEMM, 8-phase (T3+T4+T5), 256x256 tile, BK=64, 8 waves.
// v2: BALANCED ds_reads 12/8/4/0 (was 20/4/0/0 — phase-0 serialized
// 8 waves x 20 b128 = ~1280 cyc through the LDS pipe).
// Stage order per tile T: p0:B0(T+1) p1:B1(T+1) p2:A0(T+2) p3:A1(T+2);
// vmcnt(4) at p3 retires exactly tile T+1's four halves (12 loads in flight).
// Hazard ledger: A-halves last-read at p1 (lgkm-drained + p1-end barrier)
// before A(T+2) issue at p2/p3; B-halves last-read at p2 before same-buf
// B overwrite at (T+1).p0. All guards/barriers block-uniform.
// ---------------------------------------------------------------------------
__global__ __launch_bounds__(512, 2) void k_conv8(
    const u16* __restrict__ Wm, const u16* __restrict__ Xs, float* __restrict__ out)
{
  extern __shared__ u16 smem[];           // A: [0, 32768), B: [32768, 65536) u16
  u16* As = smem;
  u16* Bs = smem + 32768;

  const uint32_t bid = blockIdx.x;
  const uint32_t swz = (bid & 7u) * 32u + (bid >> 3);   // XCD swizzle, 256%8==0
  const uint32_t n = swz >> 5, ot = (swz >> 4) & 1u, pt = swz & 15u;

  const uint32_t tid = threadIdx.x;
  const uint32_t wid = tid >> 6, lane = tid & 63u;
  const uint32_t l16 = lane & 15u, lg = lane >> 4;
  const uint32_t wm = wid >> 2, wn = wid & 3u;   // wave: M-half (128 p), N-quarter (64 o)

  const u16* wmn = Wm + (size_t)n * 512u * 4608u;
  const u16* xsn = Xs + (size_t)n * 66u * 66u * 512u;

  f32x4 acc[8][4];
  f32x4 zero = {0.f, 0.f, 0.f, 0.f};
  #pragma unroll
  for (int m = 0; m < 8; ++m)
    #pragma unroll
    for (int nn = 0; nn < 4; ++nn) acc[m][nn] = zero;

  auto stageA = [&](uint32_t Tt, uint32_t half) {
    if (Tt >= 72u) return;                      // uniform guard
    const uint32_t buf = Tt & 1u;
    const uint32_t r = Tt >> 3, i0 = (Tt & 7u) << 6;
    const uint32_t kh = r / 3u, kw = r % 3u;
    #pragma unroll
    for (uint32_t j = 0; j < 2u; ++j) {
      const uint32_t sl = tid + j * 512u;
      const uint32_t row = sl >> 3, cl = sl & 7u;
      const uint32_t csrc = cl ^ (row & 7u);    // pre-swizzled SOURCE, linear dest
      const uint32_t R = half * 128u + row;
      const uint32_t hp = pt * 4u + (R >> 6) + kh, wp = (R & 63u) + kw;
      gload16(xsn + ((size_t)hp * 66u + wp) * 512u + i0 + csrc * 8u,
              As + buf * 16384u + half * 8192u + (wid * 64u + j * 512u) * 8u);
    }
  };
  auto stageB = [&](uint32_t Tt, uint32_t half) {
    if (Tt >= 72u) return;
    const uint32_t buf = Tt & 1u;
    const uint32_t r = Tt >> 3, i0 = (Tt & 7u) << 6;
    #pragma unroll
    for (uint32_t j = 0; j < 2u; ++j) {
      const uint32_t sl = tid + j * 512u;
      const uint32_t row = sl >> 3, cl = sl & 7u;
      const uint32_t csrc = cl ^ (row & 7u);
      const uint32_t o = ot * 256u + half * 128u + row;
      gload16(wmn + (size_t)o * 4608u + r * 512u + i0 + csrc * 8u,
              Bs + buf * 16384u + half * 8192u + (wid * 64u + j * 512u) * 8u);
    }
  };

  // prologue: A(0), B(0), A(1) issued; retire tile 0 (8 loads), keep A(1) in flight
  stageA(0u, 0u); stageA(0u, 1u); stageB(0u, 0u); stageB(0u, 1u);
  stageA(1u, 0u); stageA(1u, 1u);
  asm volatile("s_waitcnt vmcnt(4)" ::: "memory");
  __builtin_amdgcn_s_barrier();

  bf16x8 a[8][2], b01[2][2], b23[2][2];

  for (uint32_t T = 0; T < 72u; ++T) {
    const uint32_t buf = T & 1u;
    const u16* Ab = As + buf * 16384u;
    const u16* Bb = Bs + buf * 16384u;

    // ---- phase 0: read a[0..3] + b01 (12); MFMA (m0-3, n0-1) ----
    #pragma unroll
    for (uint32_t m = 0; m < 4u; ++m) {
      const uint32_t row = wm * 128u + m * 16u + l16;
      #pragma unroll
      for (uint32_t k = 0; k < 2u; ++k) {
        const uint32_t c = (k * 4u + lg) ^ (row & 7u);
        a[m][k] = *(const bf16x8*)(Ab + row * 64u + c * 8u);
      }
    }
    #pragma unroll
    for (uint32_t nn = 0; nn < 2u; ++nn) {
      const uint32_t row = wn * 64u + nn * 16u + l16;
      #pragma unroll
      for (uint32_t k = 0; k < 2u; ++k) {
        const uint32_t c = (k * 4u + lg) ^ (row & 7u);
        b01[nn][k] = *(const bf16x8*)(Bb + row * 64u + c * 8u);
      }
    }
    stageB(T + 1u, 0u);
    __builtin_amdgcn_s_barrier();
    asm volatile("s_waitcnt lgkmcnt(0)" ::: "memory");
    __builtin_amdgcn_sched_barrier(0);
    __builtin_amdgcn_s_setprio(1);
    #pragma unroll
    for (uint32_t m = 0; m < 4u; ++m)
      #pragma unroll
      for (uint32_t nn = 0; nn < 2u; ++nn)
        #pragma unroll
        for (uint32_t k = 0; k < 2u; ++k)
          acc[m][nn] = __builtin_amdgcn_mfma_f32_16x16x32_bf16(a[m][k], b01[nn][k], acc[m][nn], 0, 0, 0);
    __builtin_amdgcn_s_setprio(0);
    __builtin_amdgcn_s_barrier();

    // ---- phase 1: read a[4..7] (8); MFMA (m4-7, n0-1) ----
    #pragma unroll
    for (uint32_t m = 0; m < 4u; ++m) {
      const uint32_t row = wm * 128u + (m + 4u) * 16u + l16;
      #pragma unroll
      for (uint32_t k = 0; k < 2u; ++k) {
        const uint32_t c = (k * 4u + lg) ^ (row & 7u);
        a[m + 4u][k] = *(const bf16x8*)(Ab + row * 64u + c * 8u);
      }
    }
    stageB(T + 1u, 1u);
    __builtin_amdgcn_s_barrier();
    asm volatile("s_waitcnt lgkmcnt(0)" ::: "memory");
    __builtin_amdgcn_sched_barrier(0);
    __builtin_amdgcn_s_setprio(1);
    #pragma unroll
    for (uint32_t m = 0; m < 4u; ++m)
      #pragma unroll
      for (uint32_t nn = 0; nn < 2u; ++nn)
        #pragma unroll
        for (uint32_t k = 0; k < 2u; ++k)
          acc[m + 4u][nn] = __builtin_amdgcn_mfma_f32_16x16x32_bf16(a[m + 4u][k], b01[nn][k], acc[m + 4u][nn], 0, 0, 0);
    __builtin_amdgcn_s_setprio(0);
    __builtin_amdgcn_s_barrier();

    // ---- phase 2: read b23 (4); MFMA (m0-3, n2-3) ----
    #pragma unroll
    for (uint32_t nn = 0; nn < 2u; ++nn) {
      const uint32_t row = wn * 64u + (nn + 2u) * 16u + l16;
      #pragma unroll
      for (uint32_t k = 0; k < 2u; ++k) {
        const uint32_t c = (k * 4u + lg) ^ (row & 7u);
        b23[nn][k] = *(const bf16x8*)(Bb + row * 64u + c * 8u);
      }
    }
    stageA(T + 2u, 0u);
    __builtin_amdgcn_s_barrier();
    asm volatile("s_waitcnt lgkmcnt(0)" ::: "memory");
    __builtin_amdgcn_sched_barrier(0);
    __builtin_amdgcn_s_setprio(1);
    #pragma unroll
    for (uint32_t m = 0; m < 4u; ++m)
      #pragma unroll
      for (uint32_t nn = 0; nn < 2u; ++nn)
        #pragma unroll
        for (uint32_t k = 0; k < 2u; ++k)
          acc[m][nn + 2u] = __builtin_amdgcn_mfma_f32_16x16x32_bf16(a[m][k], b23[nn][k], acc[m][nn + 2u], 0, 0, 0);
    __builtin_amdgcn_s_setprio(0);
    __builtin_amdgcn_s_barrier();

    // ---- phase 3: no reads; MFMA (m4-7, n2-3); vmcnt(4) publishes tile T+1 ----
    stageA(T + 2u, 1u);
    __builtin_amdgcn_s_barrier();
    __builtin_amdgcn_s_setprio(1);
    #pragma unroll
    for (uint32_t m = 0; m < 4u; ++m)
      #pragma unroll
      for (uint32_t nn = 0; nn < 2u; ++nn)
        #pragma unroll
        for (uint32_t k = 0; k < 2u; ++k)
          acc[m + 4u][nn + 2u] = __builtin_amdgcn_mfma_f32_16x16x32_bf16(a[m + 4u][k], b23[nn][k], acc[m + 4u][nn + 2u], 0, 0, 0);
    __builtin_amdgcn_s_setprio(0);
    if (T < 70u) {
      asm volatile("s_waitcnt vmcnt(4)" ::: "memory");
    } else {
      asm volatile("s_waitcnt vmcnt(0)" ::: "memory");
    }
    __builtin_amdgcn_s_barrier();
  }

  // C[p][o]: lane reg q -> p = pbase + m*16 + lg*4 + q (contiguous), o = obase + nn*16 + l16
  float* op = out + ((size_t)n * 512u + ot * 256u + wn * 64u) * 4096u + pt * 256u + wm * 128u;
  #pragma unroll
  for (uint32_t m = 0; m < 8u; ++m)
    #pragma unroll
    for (uint32_t nn = 0; nn < 4u; ++nn)
      *(f32x4*)(op + (size_t)(nn * 16u + l16) * 4096u + m * 16u + lg * 4u) = acc[m][nn];
}

extern "C" void kernel_launch(void* const* d_in, const int* in_sizes, int n_in,
                              void* d_out, int out_size, void* d_ws, size_t ws_size,
                              hipStream_t stream) {
  const float* x       = (const float*)d_in[0];
  const float* style   = (const float*)d_in[1];
  const float* weight  = (const float*)d_in[2];
  const float* style_w = (const float*)d_in[3];
  const float* style_b = (const float*)d_in[4];
  float* out = (float*)d_out;

  if (ws_size < (size_t)WS_NEED) return;  // loud failure (output stays wrong)

  char* ws = (char*)d_ws;
  float* s  = (float*)(ws + S_OFF);
  u16*   wm = (u16*)(ws + WM_OFF);
  u16*   xs = (u16*)(ws + XS_OFF);

  (void)hipFuncSetAttribute((const void*)k_conv8,
                            hipFuncAttributeMaxDynamicSharedMemorySize, 131072);

  hipLaunchKernelGGL(k_style,  dim3(16),   dim3(256), 0, stream, style, style_w, style_b, s);
  hipLaunchKernelGGL(k_wmod3,  dim3(512),  dim3(256), 0, stream, weight, s, wm);
  hipLaunchKernelGGL(k_border, dim3(520),  dim3(256), 0, stream, xs);
  hipLaunchKernelGGL(k_xpose,  dim3(512),  dim3(256), 0, stream, x, xs);
  hipLaunchKernelGGL(k_conv8,  dim3(256),  dim3(512), 131072, stream, wm, xs, out);
}

// Round 8
// 288.563 us; speedup vs baseline: 1.5026x; 1.0448x over previous
//
#include <hip/hip_runtime.h>
#include <stdint.h>

typedef unsigned short u16;
typedef __bf16 bf16x8 __attribute__((ext_vector_type(8)));
typedef float f32x4 __attribute__((ext_vector_type(4)));

#define SCALE_F 0.014731391274719742f   // 1/sqrt(512*9)

// ---- workspace layout (bytes) ----
#define S_OFF   0u          // s[8][512] f32               (16 KB)
#define DM_OFF  16384u      // dm[8][512] f32               (16 KB)
#define WT_OFF  32768u      // wt bf16 [512 o][4608 k']     (4.5 MB), k' = r*512+i
#define XS_OFF  4751360u    // Xs bf16 [8][66][66][512]     (35.68 MB), = x*s, chan-innermost
#define WS_NEED 40435712u

__device__ __forceinline__ u16 f2bf(float f) {
  union { float f; uint32_t u; } c; c.f = f;
  return (u16)((c.u + 0x7FFFu + ((c.u >> 16) & 1u)) >> 16);  // RNE
}

__device__ __forceinline__ void gload16(const void* g, void* l) {
  __builtin_amdgcn_global_load_lds(
      (const __attribute__((address_space(1))) uint32_t*)g,
      (__attribute__((address_space(3))) uint32_t*)l, 16, 0, 0);
}

// K1: s[n][c] = style[n] . style_w[c] + style_b[c]   (grid 16x256)
__global__ void k_style(const float* __restrict__ style, const float* __restrict__ sw,
                        const float* __restrict__ sb, float* __restrict__ s) {
  int t = blockIdx.x * 256 + threadIdx.x;          // 4096
  int n = t >> 9, c = t & 511;
  const float4* wr = (const float4*)(sw + (size_t)c * 512);
  const float4* st = (const float4*)(style + (size_t)n * 512);
  float acc = 0.f;
  #pragma unroll 4
  for (int d = 0; d < 128; ++d) {
    float4 a = st[d], b = wr[d];
    acc += a.x * b.x + a.y * b.y + a.z * b.z + a.w * b.w;
  }
  s[t] = acc + sb[c];
}

// K2: one block per o. Loads w[o] (scaled by SCALE) + s into LDS; computes
// dm[n][o] = rsqrt(sum_i s^2 * wsq + 1e-8) in-block; writes wt[o][r*512+i] =
// bf16(SCALE*w[o][i][r]) (n-INDEPENDENT — modulation moved to X, demod to
// conv epilogue). Coalesced reads/writes; stride-9 LDS reads bank-coprime.
__global__ __launch_bounds__(256) void k_wt(
    const float* __restrict__ w, const float* __restrict__ s,
    u16* __restrict__ wt, float* __restrict__ dm) {
  __shared__ float wlds[4608];
  __shared__ float slds[4096];
  __shared__ float red[8][4];
  const uint32_t o = blockIdx.x, t = threadIdx.x;
  const uint32_t lane = t & 63u, wv = t >> 6;
  #pragma unroll
  for (uint32_t c = 0; c < 18u; ++c)
    wlds[c * 256u + t] = w[(size_t)o * 4608u + c * 256u + t] * SCALE_F;
  #pragma unroll
  for (uint32_t c = 0; c < 16u; ++c)
    slds[c * 256u + t] = s[c * 256u + t];
  __syncthreads();
  float part[8] = {0.f, 0.f, 0.f, 0.f, 0.f, 0.f, 0.f, 0.f};
  #pragma unroll
  for (uint32_t hh = 0; hh < 2u; ++hh) {        // i = hh*256 + t
    uint32_t i = hh * 256u + t;
    float q = 0.f;
    #pragma unroll
    for (uint32_t r = 0; r < 9u; ++r) { float a = wlds[i * 9u + r]; q += a * a; }
    #pragma unroll
    for (uint32_t nn = 0; nn < 8u; ++nn) {
      float sv = slds[nn * 512u + i];
      part[nn] += q * sv * sv;
    }
  }
  #pragma unroll
  for (uint32_t nn = 0; nn < 8u; ++nn) {
    float v = part[nn];
    #pragma unroll
    for (uint32_t off = 32u; off >= 1u; off >>= 1) v += __shfl_down(v, off);
    if (lane == 0u) red[nn][wv] = v;
  }
  __syncthreads();
  if (t < 8u)
    dm[t * 512u + o] = rsqrtf(red[t][0] + red[t][1] + red[t][2] + red[t][3] + 1e-8f);
  // transpose-write wt (wlds unchanged since first sync; no barrier needed)
  #pragma unroll 2
  for (uint32_t c = 0; c < 18u; ++c) {
    uint32_t idx = c * 256u + t;
    uint32_t i = idx & 511u, r = idx >> 9;
    wt[(size_t)o * 4608u + idx] = f2bf(wlds[i * 9u + r]);
  }
}

// K3: zero ONLY the border of Xs (2.13 MB). Interior overwritten by k_xpose.
__global__ void k_border(u16* __restrict__ xs) {
  uint32_t tg = blockIdx.x * 256u + threadIdx.x;   // 133,120
  uint32_t q = tg >> 6;        // border pixel id, 64 uint4 per pixel (512 u16)
  uint32_t r = tg & 63u;
  uint32_t n = q / 260u, b = q % 260u;
  uint32_t h, w;
  if (b < 66u)        { h = 0u;  w = b; }
  else if (b < 132u)  { h = 65u; w = b - 66u; }
  else { uint32_t c = b - 132u; h = 1u + (c >> 1); w = (c & 1u) * 65u; }
  uint4 z = {0u, 0u, 0u, 0u};
  *(uint4*)(xs + (((size_t)n * 66u + h) * 66u + w) * 512u + r * 8u) = z;
}

// K4: Xs[n][hs+1][w+1][i] = bf16(x[n][i][hs][w] * s[n][i]) — NCHW f32 ->
// s-MODULATED NHWC bf16. b128 LDS writes (conflict-free bank windows).
__global__ __launch_bounds__(256) void k_xpose(const float* __restrict__ x,
                                               const float* __restrict__ s,
                                               u16* __restrict__ xs) {
  __shared__ u16 tile[64][512];   // [w][i], 64 KB
  uint32_t b = blockIdx.x, n = b >> 6, hs = b & 63u;
  uint32_t t = threadIdx.x;
  const float* xr = x + ((size_t)n * 512u * 64u + hs) * 64u;   // + i*4096 + w
  uint32_t w4 = (t & 15u) * 4u;
  uint32_t ib = (t >> 4) * 8u;                                  // 0..120
  float sv[4][8];
  #pragma unroll
  for (uint32_t p = 0; p < 4u; ++p)
    #pragma unroll
    for (uint32_t j = 0; j < 8u; ++j)
      sv[p][j] = s[n * 512u + p * 128u + ib + j];   // L1/L2-cached broadcast
  #pragma unroll
  for (uint32_t p = 0; p < 4u; ++p) {
    uint32_t i0 = p * 128u + ib;
    float4 v[8];
    #pragma unroll
    for (uint32_t j = 0; j < 8u; ++j)
      v[j] = *(const float4*)(xr + (size_t)(i0 + j) * 4096u + w4);
    #pragma unroll
    for (uint32_t k = 0; k < 4u; ++k) {
      union { u16 h[8]; uint4 q; } pk;
      #pragma unroll
      for (uint32_t j = 0; j < 8u; ++j) {
        float f = (k == 0u) ? v[j].x : (k == 1u) ? v[j].y : (k == 2u) ? v[j].z : v[j].w;
        pk.h[j] = f2bf(f * sv[p][j]);
      }
      *(uint4*)&tile[w4 + k][i0] = pk.q;        // ds_write_b128
    }
  }
  __syncthreads();
  u16* orow = xs + (((size_t)n * 66u + hs + 1u) * 66u + 1u) * 512u;  // hp=hs+1, wp=w+1
  #pragma unroll
  for (uint32_t p = 0; p < 16u; ++p) {
    uint32_t idx = p * 256u + t;
    uint32_t w = idx >> 6, i8 = (idx & 63u) * 8u;
    *(bf16x8*)(orow + (size_t)w * 512u + i8) = *(const bf16x8*)(&tile[w][i8]);
  }
}

// ---------------------------------------------------------------------------
// K5: conv implicit GEMM, 8-phase (T3+T4+T5), 256x256 tile, BK=64, 8 waves.
// C[p][o] = dm[n][o] * sum_k (X*s)[p][k] * (SCALE*w)[k][o] — demod applied as
// fp32 epilogue column-scale. B-operand wt is n-independent (4.7 MB shared by
// all blocks -> L2-resident). Balanced ds_reads 12/8/4/0; stage order
// p0:B0(T+1) p1:B1(T+1) p2:A0(T+2) p3:A1(T+2); vmcnt(4) at p3.
// ---------------------------------------------------------------------------
__global__ __launch_bounds__(512, 2) void k_conv8(
    const u16* __restrict__ Wt, const u16* __restrict__ Xs,
    const float* __restrict__ Dm, float* __restrict__ out)
{
  extern __shared__ u16 smem[];           // A: [0, 32768), B: [32768, 65536) u16
  u16* As = smem;
  u16* Bs = smem + 32768;

  const uint32_t bid = blockIdx.x;
  const uint32_t swz = (bid & 7u) * 32u + (bid >> 3);   // XCD swizzle, 256%8==0
  const uint32_t n = swz >> 5, ot = (swz >> 4) & 1u, pt = swz & 15u;

  const uint32_t tid = threadIdx.x;
  const uint32_t wid = tid >> 6, lane = tid & 63u;
  const uint32_t l16 = lane & 15u, lg = lane >> 4;
  const uint32_t wm = wid >> 2, wn = wid & 3u;   // wave: M-half (128 p), N-quarter (64 o)

  const u16* xsn = Xs + (size_t)n * 66u * 66u * 512u;

  f32x4 acc[8][4];
  f32x4 zero = {0.f, 0.f, 0.f, 0.f};
  #pragma unroll
  for (int m = 0; m < 8; ++m)
    #pragma unroll
    for (int nn = 0; nn < 4; ++nn) acc[m][nn] = zero;

  auto stageA = [&](uint32_t Tt, uint32_t half) {
    if (Tt >= 72u) return;                      // uniform guard
    const uint32_t buf = Tt & 1u;
    const uint32_t r = Tt >> 3, i0 = (Tt & 7u) << 6;
    const uint32_t kh = r / 3u, kw = r % 3u;
    #pragma unroll
    for (uint32_t j = 0; j < 2u; ++j) {
      const uint32_t sl = tid + j * 512u;
      const uint32_t row = sl >> 3, cl = sl & 7u;
      const uint32_t csrc = cl ^ (row & 7u);    // pre-swizzled SOURCE, linear dest
      const uint32_t R = half * 128u + row;
      const uint32_t hp = pt * 4u + (R >> 6) + kh, wp = (R & 63u) + kw;
      gload16(xsn + ((size_t)hp * 66u + wp) * 512u + i0 + csrc * 8u,
              As + buf * 16384u + half * 8192u + (wid * 64u + j * 512u) * 8u);
    }
  };
  auto stageB = [&](uint32_t Tt, uint32_t half) {
    if (Tt >= 72u) return;
    const uint32_t buf = Tt & 1u;
    const uint32_t r = Tt >> 3, i0 = (Tt & 7u) << 6;
    #pragma unroll
    for (uint32_t j = 0; j < 2u; ++j) {
      const uint32_t sl = tid + j * 512u;
      const uint32_t row = sl >> 3, cl = sl & 7u;
      const uint32_t csrc = cl ^ (row & 7u);
      const uint32_t o = ot * 256u + half * 128u + row;
      gload16(Wt + (size_t)o * 4608u + r * 512u + i0 + csrc * 8u,
              Bs + buf * 16384u + half * 8192u + (wid * 64u + j * 512u) * 8u);
    }
  };

  // prologue: A(0), B(0), A(1) issued; retire tile 0 (8 loads), keep A(1) in flight
  stageA(0u, 0u); stageA(0u, 1u); stageB(0u, 0u); stageB(0u, 1u);
  stageA(1u, 0u); stageA(1u, 1u);
  asm volatile("s_waitcnt vmcnt(4)" ::: "memory");
  __builtin_amdgcn_s_barrier();

  bf16x8 a[8][2], b01[2][2], b23[2][2];

  for (uint32_t T = 0; T < 72u; ++T) {
    const uint32_t buf = T & 1u;
    const u16* Ab = As + buf * 16384u;
    const u16* Bb = Bs + buf * 16384u;

    // ---- phase 0: read a[0..3] + b01 (12); MFMA (m0-3, n0-1) ----
    #pragma unroll
    for (uint32_t m = 0; m < 4u; ++m) {
      const uint32_t row = wm * 128u + m * 16u + l16;
      #pragma unroll
      for (uint32_t k = 0; k < 2u; ++k) {
        const uint32_t c = (k * 4u + lg) ^ (row & 7u);
        a[m][k] = *(const bf16x8*)(Ab + row * 64u + c * 8u);
      }
    }
    #pragma unroll
    for (uint32_t nn = 0; nn < 2u; ++nn) {
      const uint32_t row = wn * 64u + nn * 16u + l16;
      #pragma unroll
      for (uint32_t k = 0; k < 2u; ++k) {
        const uint32_t c = (k * 4u + lg) ^ (row & 7u);
        b01[nn][k] = *(const bf16x8*)(Bb + row * 64u + c * 8u);
      }
    }
    stageB(T + 1u, 0u);
    __builtin_amdgcn_s_barrier();
    asm volatile("s_waitcnt lgkmcnt(0)" ::: "memory");
    __builtin_amdgcn_sched_barrier(0);
    __builtin_amdgcn_s_setprio(1);
    #pragma unroll
    for (uint32_t m = 0; m < 4u; ++m)
      #pragma unroll
      for (uint32_t nn = 0; nn < 2u; ++nn)
        #pragma unroll
        for (uint32_t k = 0; k < 2u; ++k)
          acc[m][nn] = __builtin_amdgcn_mfma_f32_16x16x32_bf16(a[m][k], b01[nn][k], acc[m][nn], 0, 0, 0);
    __builtin_amdgcn_s_setprio(0);
    __builtin_amdgcn_s_barrier();

    // ---- phase 1: read a[4..7] (8); MFMA (m4-7, n0-1) ----
    #pragma unroll
    for (uint32_t m = 0; m < 4u; ++m) {
      const uint32_t row = wm * 128u + (m + 4u) * 16u + l16;
      #pragma unroll
      for (uint32_t k = 0; k < 2u; ++k) {
        const uint32_t c = (k * 4u + lg) ^ (row & 7u);
        a[m + 4u][k] = *(const bf16x8*)(Ab + row * 64u + c * 8u);
      }
    }
    stageB(T + 1u, 1u);
    __builtin_amdgcn_s_barrier();
    asm volatile("s_waitcnt lgkmcnt(0)" ::: "memory");
    __builtin_amdgcn_sched_barrier(0);
    __builtin_amdgcn_s_setprio(1);
    #pragma unroll
    for (uint32_t m = 0; m < 4u; ++m)
      #pragma unroll
      for (uint32_t nn = 0; nn < 2u; ++nn)
        #pragma unroll
        for (uint32_t k = 0; k < 2u; ++k)
          acc[m + 4u][nn] = __builtin_amdgcn_mfma_f32_16x16x32_bf16(a[m + 4u][k], b01[nn][k], acc[m + 4u][nn], 0, 0, 0);
    __builtin_amdgcn_s_setprio(0);
    __builtin_amdgcn_s_barrier();

    // ---- phase 2: read b23 (4); MFMA (m0-3, n2-3) ----
    #pragma unroll
    for (uint32_t nn = 0; nn < 2u; ++nn) {
      const uint32_t row = wn * 64u + (nn + 2u) * 16u + l16;
      #pragma unroll
      for (uint32_t k = 0; k < 2u; ++k) {
        const uint32_t c = (k * 4u + lg) ^ (row & 7u);
        b23[nn][k] = *(const bf16x8*)(Bb + row * 64u + c * 8u);
      }
    }
    stageA(T + 2u, 0u);
    __builtin_amdgcn_s_barrier();
    asm volatile("s_waitcnt lgkmcnt(0)" ::: "memory");
    __builtin_amdgcn_sched_barrier(0);
    __builtin_amdgcn_s_setprio(1);
    #pragma unroll
    for (uint32_t m = 0; m < 4u; ++m)
      #pragma unroll
      for (uint32_t nn = 0; nn < 2u; ++nn)
        #pragma unroll
        for (uint32_t k = 0; k < 2u; ++k)
          acc[m][nn + 2u] = __builtin_amdgcn_mfma_f32_16x16x32_bf16(a[m][k], b23[nn][k], acc[m][nn + 2u], 0, 0, 0);
    __builtin_amdgcn_s_setprio(0);
    __builtin_amdgcn_s_barrier();

    // ---- phase 3: no reads; MFMA (m4-7, n2-3); vmcnt(4) publishes tile T+1 ----
    stageA(T + 2u, 1u);
    __builtin_amdgcn_s_barrier();
    __builtin_amdgcn_s_setprio(1);
    #pragma unroll
    for (uint32_t m = 0; m < 4u; ++m)
      #pragma unroll
      for (uint32_t nn = 0; nn < 2u; ++nn)
        #pragma unroll
        for (uint32_t k = 0; k < 2u; ++k)
          acc[m + 4u][nn + 2u] = __builtin_amdgcn_mfma_f32_16x16x32_bf16(a[m + 4u][k], b23[nn][k], acc[m + 4u][nn + 2u], 0, 0, 0);
    __builtin_amdgcn_s_setprio(0);
    if (T < 70u) {
      asm volatile("s_waitcnt vmcnt(4)" ::: "memory");
    } else {
      asm volatile("s_waitcnt vmcnt(0)" ::: "memory");
    }
    __builtin_amdgcn_s_barrier();
  }

  // epilogue: demod column scale (fp32), then store.
  // C[p][o]: lane reg q -> p = pbase + m*16 + lg*4 + q (contiguous), o = obase + nn*16 + l16
  float dmv[4];
  #pragma unroll
  for (uint32_t nn = 0; nn < 4u; ++nn)
    dmv[nn] = Dm[n * 512u + ot * 256u + wn * 64u + nn * 16u + l16];
  float* op = out + ((size_t)n * 512u + ot * 256u + wn * 64u) * 4096u + pt * 256u + wm * 128u;
  #pragma unroll
  for (uint32_t m = 0; m < 8u; ++m)
    #pragma unroll
    for (uint32_t nn = 0; nn < 4u; ++nn)
      *(f32x4*)(op + (size_t)(nn * 16u + l16) * 4096u + m * 16u + lg * 4u) = acc[m][nn] * dmv[nn];
}

extern "C" void kernel_launch(void* const* d_in, const int* in_sizes, int n_in,
                              void* d_out, int out_size, void* d_ws, size_t ws_size,
                              hipStream_t stream) {
  const float* x       = (const float*)d_in[0];
  const float* style   = (const float*)d_in[1];
  const float* weight  = (const float*)d_in[2];
  const float* style_w = (const float*)d_in[3];
  const float* style_b = (const float*)d_in[4];
  float* out = (float*)d_out;

  if (ws_size < (size_t)WS_NEED) return;  // loud failure (output stays wrong)

  char* ws = (char*)d_ws;
  float* s  = (float*)(ws + S_OFF);
  float* dm = (float*)(ws + DM_OFF);
  u16*   wt = (u16*)(ws + WT_OFF);
  u16*   xs = (u16*)(ws + XS_OFF);

  (void)hipFuncSetAttribute((const void*)k_conv8,
                            hipFuncAttributeMaxDynamicSharedMemorySize, 131072);

  hipLaunchKernelGGL(k_style,  dim3(16),   dim3(256), 0, stream, style, style_w, style_b, s);
  hipLaunchKernelGGL(k_wt,     dim3(512),  dim3(256), 0, stream, weight, s, wt, dm);
  hipLaunchKernelGGL(k_border, dim3(520),  dim3(256), 0, stream, xs);
  hipLaunchKernelGGL(k_xpose,  dim3(512),  dim3(256), 0, stream, x, s, xs);
  hipLaunchKernelGGL(k_conv8,  dim3(256),  dim3(512), 131072, stream, wt, xs, dm, out);
}

// Round 11
// 287.338 us; speedup vs baseline: 1.5090x; 1.0043x over previous
//
#include <hip/hip_runtime.h>
#include <stdint.h>

typedef unsigned short u16;
typedef __bf16 bf16x8 __attribute__((ext_vector_type(8)));
typedef float f32x4 __attribute__((ext_vector_type(4)));

#define SCALE_F 0.014731391274719742f   // 1/sqrt(512*9)

// ---- workspace layout (bytes) ----
#define S_OFF   0u          // s[8][512] f32               (16 KB)
#define DM_OFF  16384u      // dm[8][512] f32               (16 KB)
#define WT_OFF  32768u      // Wt2 bf16 fragment-linear [o/16][k'/32][lane][8] (4.5 MB)
#define XS_OFF  4751360u    // Xs bf16 [8][66][66][512]     (35.68 MB), = x*s, chan-innermost
#define WS_NEED 40435712u

__device__ __forceinline__ u16 f2bf(float f) {
  union { float f; uint32_t u; } c; c.f = f;
  return (u16)((c.u + 0x7FFFu + ((c.u >> 16) & 1u)) >> 16);  // RNE
}

__device__ __forceinline__ void gload16(const void* g, void* l) {
  __builtin_amdgcn_global_load_lds(
      (const __attribute__((address_space(1))) uint32_t*)g,
      (__attribute__((address_space(3))) uint32_t*)l, 16, 0, 0);
}

// K1: s[n][c] = style[n] . style_w[c] + style_b[c]   (grid 16x256)
__global__ void k_style(const float* __restrict__ style, const float* __restrict__ sw,
                        const float* __restrict__ sb, float* __restrict__ s) {
  int t = blockIdx.x * 256 + threadIdx.x;          // 4096
  int n = t >> 9, c = t & 511;
  const float4* wr = (const float4*)(sw + (size_t)c * 512);
  const float4* st = (const float4*)(style + (size_t)n * 512);
  float acc = 0.f;
  #pragma unroll 4
  for (int d = 0; d < 128; ++d) {
    float4 a = st[d], b = wr[d];
    acc += a.x * b.x + a.y * b.y + a.z * b.z + a.w * b.w;
  }
  s[t] = acc + sb[c];
}

// K2: one block per o. dm[n][o] in-block; writes Wt2 in MFMA-FRAGMENT-LINEAR
// layout: frag (ob = o>>4, kc = k'>>5) is 64 lanes x 16B contiguous;
// lane = (o&15) + 16*lg holds k' = kc*32 + lg*8 + j.  k' = r*512 + i.
__global__ __launch_bounds__(256) void k_wt(
    const float* __restrict__ w, const float* __restrict__ s,
    u16* __restrict__ wt2, float* __restrict__ dm) {
  __shared__ float wlds[4608];
  __shared__ float slds[4096];
  __shared__ float red[8][4];
  const uint32_t o = blockIdx.x, t = threadIdx.x;
  const uint32_t lane = t & 63u, wv = t >> 6;
  #pragma unroll
  for (uint32_t c = 0; c < 18u; ++c)
    wlds[c * 256u + t] = w[(size_t)o * 4608u + c * 256u + t] * SCALE_F;
  #pragma unroll
  for (uint32_t c = 0; c < 16u; ++c)
    slds[c * 256u + t] = s[c * 256u + t];
  __syncthreads();
  float part[8] = {0.f, 0.f, 0.f, 0.f, 0.f, 0.f, 0.f, 0.f};
  #pragma unroll
  for (uint32_t hh = 0; hh < 2u; ++hh) {        // i = hh*256 + t
    uint32_t i = hh * 256u + t;
    float q = 0.f;
    #pragma unroll
    for (uint32_t r = 0; r < 9u; ++r) { float a = wlds[i * 9u + r]; q += a * a; }
    #pragma unroll
    for (uint32_t nn = 0; nn < 8u; ++nn) {
      float sv = slds[nn * 512u + i];
      part[nn] += q * sv * sv;
    }
  }
  #pragma unroll
  for (uint32_t nn = 0; nn < 8u; ++nn) {
    float v = part[nn];
    #pragma unroll
    for (uint32_t off = 32u; off >= 1u; off >>= 1) v += __shfl_down(v, off);
    if (lane == 0u) red[nn][wv] = v;
  }
  __syncthreads();
  if (t < 8u)
    dm[t * 512u + o] = rsqrtf(red[t][0] + red[t][1] + red[t][2] + red[t][3] + 1e-8f);
  const uint32_t ob = o >> 4, ol = o & 15u;
  #pragma unroll 2
  for (uint32_t c = 0; c < 18u; ++c) {
    uint32_t idx = c * 256u + t;                 // k'
    uint32_t i = idx & 511u, r = idx >> 9;
    uint32_t pos = ((ob * 144u + (idx >> 5)) << 9) + (((idx >> 3) & 3u) << 7)
                 + (ol << 3) + (idx & 7u);
    wt2[pos] = f2bf(wlds[i * 9u + r]);
  }
}

// K3: zero ONLY the border of Xs (2.13 MB). Interior overwritten by k_xpose.
__global__ void k_border(u16* __restrict__ xs) {
  uint32_t tg = blockIdx.x * 256u + threadIdx.x;   // 133,120
  uint32_t q = tg >> 6;        // border pixel id, 64 uint4 per pixel (512 u16)
  uint32_t r = tg & 63u;
  uint32_t n = q / 260u, b = q % 260u;
  uint32_t h, w;
  if (b < 66u)        { h = 0u;  w = b; }
  else if (b < 132u)  { h = 65u; w = b - 66u; }
  else { uint32_t c = b - 132u; h = 1u + (c >> 1); w = (c & 1u) * 65u; }
  uint4 z = {0u, 0u, 0u, 0u};
  *(uint4*)(xs + (((size_t)n * 66u + h) * 66u + w) * 512u + r * 8u) = z;
}

// K4: Xs[n][hs+1][w+1][i] = bf16(x[n][i][hs][w] * s[n][i]) — NCHW f32 ->
// s-modulated NHWC bf16. v3: NO LDS — each thread holds 8 consecutive i per w,
// packs bf16x8 and stores DIRECT to global (64B segments).
__global__ __launch_bounds__(256) void k_xpose(const float* __restrict__ x,
                                               const float* __restrict__ s,
                                               u16* __restrict__ xs) {
  uint32_t b = blockIdx.x, n = b >> 6, hs = b & 63u;
  uint32_t t = threadIdx.x;
  const float* xr = x + ((size_t)n * 512u * 64u + hs) * 64u;   // + i*4096 + w
  uint32_t w4 = (t & 15u) * 4u;
  uint32_t ib = (t >> 4) * 8u;                                  // 0..120
  u16* orow = xs + (((size_t)n * 66u + hs + 1u) * 66u + 1u) * 512u;  // hp=hs+1, wp=w+1
  #pragma unroll
  for (uint32_t p = 0; p < 4u; ++p) {
    uint32_t i0 = p * 128u + ib;
    float4 v[8];
    #pragma unroll
    for (uint32_t j = 0; j < 8u; ++j)
      v[j] = *(const float4*)(xr + (size_t)(i0 + j) * 4096u + w4);
    float sv[8];
    #pragma unroll
    for (uint32_t j = 0; j < 8u; ++j) sv[j] = s[n * 512u + i0 + j];
    #pragma unroll
    for (uint32_t k = 0; k < 4u; ++k) {
      union { u16 h[8]; uint4 q; } pk;
      #pragma unroll
      for (uint32_t j = 0; j < 8u; ++j) {
        float f = (k == 0u) ? v[j].x : (k == 1u) ? v[j].y : (k == 2u) ? v[j].z : v[j].w;
        pk.h[j] = f2bf(f * sv[j]);
      }
      *(uint4*)(orow + (size_t)(w4 + k) * 512u + i0) = pk.q;   // 16B store, 64B segments
    }
  }
}

// ---------------------------------------------------------------------------
// K5 v3: conv implicit GEMM, 256x256 tile, BK=64, 8 waves.  FREE-RUN schedule:
// ONE barrier per tile; B-operand loaded DIRECT from fragment-linear Wt2
// (1KB contiguous per wave-frag, L2/L3-hot) — no LDS for B; LDS = A only
// (64 KB double-buffer).  Per tile, per thread (FIFO vmem order):
//   p0: issue A(T+1)h0[2 gload_lds]; 8 ds a03; lgkm0+SB; Q0 = m03 x b01
//   p1: issue A(T+1)h1[2];           8 ds a47; lgkm0+SB; Q1 = m47 x b01
//   p2: issue b01(T+1)[4 loads]; vmcnt(8)+SB (b23(T) ready); Q2 = m03 x b23
//   p3: Q3 = m47 x b23; issue b23(T+1)[4]; vmcnt(4)+SB; s_barrier
// All s_barriers are block-uniform (1 prologue + 72 loop) — no deadlock path.
// ---------------------------------------------------------------------------
__global__ __launch_bounds__(512, 2) void k_conv8(
    const u16* __restrict__ Wt2, const u16* __restrict__ Xs,
    const float* __restrict__ Dm, float* __restrict__ out)
{
  extern __shared__ u16 smem[];           // A: [2][256][64] u16 = 64 KB
  u16* As = smem;

  const uint32_t bid = blockIdx.x;
  const uint32_t swz = (bid & 7u) * 32u + (bid >> 3);   // XCD swizzle, 256%8==0
  const uint32_t n = swz >> 5, ot = (swz >> 4) & 1u, pt = swz & 15u;

  const uint32_t tid = threadIdx.x;
  const uint32_t wid = tid >> 6, lane = tid & 63u;
  const uint32_t l16 = lane & 15u, lg = lane >> 4;
  const uint32_t wm = wid >> 2, wn = wid & 3u;   // wave: M-half (128 p), N-quarter (64 o)

  const u16* xsn = Xs + (size_t)n * 66u * 66u * 512u;

  f32x4 acc[8][4];
  f32x4 zero = {0.f, 0.f, 0.f, 0.f};
  #pragma unroll
  for (int m = 0; m < 8; ++m)
    #pragma unroll
    for (int nn = 0; nn < 4; ++nn) acc[m][nn] = zero;

  auto stageA = [&](uint32_t Tt, uint32_t half) {
    if (Tt >= 72u) return;                      // uniform guard
    const uint32_t buf = Tt & 1u;
    const uint32_t r = Tt >> 3, i0 = (Tt & 7u) << 6;
    const uint32_t kh = r / 3u, kw = r % 3u;
    #pragma unroll
    for (uint32_t j = 0; j < 2u; ++j) {
      const uint32_t sl = tid + j * 512u;
      const uint32_t row = sl >> 3, cl = sl & 7u;
      const uint32_t csrc = cl ^ (row & 7u);    // pre-swizzled SOURCE, linear dest
      const uint32_t R = half * 128u + row;
      const uint32_t hp = pt * 4u + (R >> 6) + kh, wp = (R & 63u) + kw;
      gload16(xsn + ((size_t)hp * 66u + wp) * 512u + i0 + csrc * 8u,
              As + buf * 16384u + half * 8192u + (wid * 64u + j * 512u) * 8u);
    }
  };

  // B-fragment load: frag (ob, kc) = 64 lanes x 16B contiguous in Wt2.
  auto bload = [&](uint32_t nn, uint32_t kk, uint32_t Tt) -> bf16x8 {
    const uint32_t ob = ot * 16u + wn * 4u + nn;
    const uint32_t kc = (Tt >> 3) * 16u + (Tt & 7u) * 2u + kk;
    return *(const bf16x8*)(Wt2 + (((size_t)(ob * 144u + kc)) << 9) + (lane << 3));
  };

  bf16x8 a[8][2], b01[2][2], b23[2][2];

  // prologue: stage A(0); load b(0); drain; publish.
  stageA(0u, 0u); stageA(0u, 1u);
  #pragma unroll
  for (uint32_t nn = 0; nn < 2u; ++nn)
    #pragma unroll
    for (uint32_t k = 0; k < 2u; ++k) {
      b01[nn][k] = bload(nn, k, 0u);
      b23[nn][k] = bload(nn + 2u, k, 0u);
    }
  asm volatile("s_waitcnt vmcnt(0)" ::: "memory");
  __builtin_amdgcn_sched_barrier(0);
  __builtin_amdgcn_s_barrier();

  for (uint32_t T = 0; T < 72u; ++T) {
    const uint32_t buf = T & 1u;
    const u16* Ab = As + buf * 16384u;

    // ---- p0: stage A(T+1)h0; read a03; Q0 = m0-3 x b01 ----
    stageA(T + 1u, 0u);
    #pragma unroll
    for (uint32_t m = 0; m < 4u; ++m) {
      const uint32_t row = wm * 128u + m * 16u + l16;
      #pragma unroll
      for (uint32_t k = 0; k < 2u; ++k) {
        const uint32_t c = (k * 4u + lg) ^ (row & 7u);
        a[m][k] = *(const bf16x8*)(Ab + row * 64u + c * 8u);
      }
    }
    asm volatile("s_waitcnt lgkmcnt(0)" ::: "memory");
    __builtin_amdgcn_sched_barrier(0);
    __builtin_amdgcn_s_setprio(1);
    #pragma unroll
    for (uint32_t m = 0; m < 4u; ++m)
      #pragma unroll
      for (uint32_t nn = 0; nn < 2u; ++nn)
        #pragma unroll
        for (uint32_t k = 0; k < 2u; ++k)
          acc[m][nn] = __builtin_amdgcn_mfma_f32_16x16x32_bf16(a[m][k], b01[nn][k], acc[m][nn], 0, 0, 0);
    __builtin_amdgcn_s_setprio(0);

    // ---- p1: stage A(T+1)h1; read a47; Q1 = m4-7 x b01 ----
    stageA(T + 1u, 1u);
    #pragma unroll
    for (uint32_t m = 0; m < 4u; ++m) {
      const uint32_t row = wm * 128u + (m + 4u) * 16u + l16;
      #pragma unroll
      for (uint32_t k = 0; k < 2u; ++k) {
        const uint32_t c = (k * 4u + lg) ^ (row & 7u);
        a[m + 4u][k] = *(const bf16x8*)(Ab + row * 64u + c * 8u);
      }
    }
    asm volatile("s_waitcnt lgkmcnt(0)" ::: "memory");
    __builtin_amdgcn_sched_barrier(0);
    __builtin_amdgcn_s_setprio(1);
    #pragma unroll
    for (uint32_t m = 0; m < 4u; ++m)
      #pragma unroll
      for (uint32_t nn = 0; nn < 2u; ++nn)
        #pragma unroll
        for (uint32_t k = 0; k < 2u; ++k)
          acc[m + 4u][nn] = __builtin_amdgcn_mfma_f32_16x16x32_bf16(a[m + 4u][k], b01[nn][k], acc[m + 4u][nn], 0, 0, 0);
    __builtin_amdgcn_s_setprio(0);

    // ---- p2: issue b01(T+1); vmcnt guards b23(T); Q2 = m0-3 x b23 ----
    if (T < 71u) {
      #pragma unroll
      for (uint32_t nn = 0; nn < 2u; ++nn)
        #pragma unroll
        for (uint32_t k = 0; k < 2u; ++k)
          b01[nn][k] = bload(nn, k, T + 1u);
      asm volatile("s_waitcnt vmcnt(8)" ::: "memory");
    } else {
      asm volatile("s_waitcnt vmcnt(0)" ::: "memory");
    }
    __builtin_amdgcn_sched_barrier(0);
    __builtin_amdgcn_s_setprio(1);
    #pragma unroll
    for (uint32_t m = 0; m < 4u; ++m)
      #pragma unroll
      for (uint32_t nn = 0; nn < 2u; ++nn)
        #pragma unroll
        for (uint32_t k = 0; k < 2u; ++k)
          acc[m][nn + 2u] = __builtin_amdgcn_mfma_f32_16x16x32_bf16(a[m][k], b23[nn][k], acc[m][nn + 2u], 0, 0, 0);
    __builtin_amdgcn_s_setprio(0);

    // ---- p3: Q3 = m4-7 x b23; issue b23(T+1); publish tile T+1 ----
    __builtin_amdgcn_s_setprio(1);
    #pragma unroll
    for (uint32_t m = 0; m < 4u; ++m)
      #pragma unroll
      for (uint32_t nn = 0; nn < 2u; ++nn)
        #pragma unroll
        for (uint32_t k = 0; k < 2u; ++k)
          acc[m + 4u][nn + 2u] = __builtin_amdgcn_mfma_f32_16x16x32_bf16(a[m + 4u][k], b23[nn][k], acc[m + 4u][nn + 2u], 0, 0, 0);
    __builtin_amdgcn_s_setprio(0);
    if (T < 71u) {
      #pragma unroll
      for (uint32_t nn = 0; nn < 2u; ++nn)
        #pragma unroll
        for (uint32_t k = 0; k < 2u; ++k)
          b23[nn][k] = bload(nn + 2u, k, T + 1u);
      asm volatile("s_waitcnt vmcnt(4)" ::: "memory");
    }
    __builtin_amdgcn_sched_barrier(0);
    __builtin_amdgcn_s_barrier();
  }

  // epilogue: demod column scale (fp32), then store.
  float dmv[4];
  #pragma unroll
  for (uint32_t nn = 0; nn < 4u; ++nn)
    dmv[nn] = Dm[n * 512u + ot * 256u + wn * 64u + nn * 16u + l16];
  float* op = out + ((size_t)n * 512u + ot * 256u + wn * 64u) * 4096u + pt * 256u + wm * 128u;
  #pragma unroll
  for (uint32_t m = 0; m < 8u; ++m)
    #pragma unroll
    for (uint32_t nn = 0; nn < 4u; ++nn)
      *(f32x4*)(op + (size_t)(nn * 16u + l16) * 4096u + m * 16u + lg * 4u) = acc[m][nn] * dmv[nn];
}

extern "C" void kernel_launch(void* const* d_in, const int* in_sizes, int n_in,
                              void* d_out, int out_size, void* d_ws, size_t ws_size,
                              hipStream_t stream) {
  const float* x       = (const float*)d_in[0];
  const float* style   = (const float*)d_in[1];
  const float* weight  = (const float*)d_in[2];
  const float* style_w = (const float*)d_in[3];
  const float* style_b = (const float*)d_in[4];
  float* out = (float*)d_out;

  if (ws_size < (size_t)WS_NEED) return;  // loud failure (output stays wrong)

  char* ws = (char*)d_ws;
  float* s  = (float*)(ws + S_OFF);
  float* dm = (float*)(ws + DM_OFF);
  u16*   wt = (u16*)(ws + WT_OFF);
  u16*   xs = (u16*)(ws + XS_OFF);

  (void)hipFuncSetAttribute((const void*)k_conv8,
                            hipFuncAttributeMaxDynamicSharedMemorySize, 65536);

  hipLaunchKernelGGL(k_style,  dim3(16),   dim3(256), 0, stream, style, style_w, style_b, s);
  hipLaunchKernelGGL(k_wt,     dim3(512),  dim3(256), 0, stream, weight, s, wt, dm);
  hipLaunchKernelGGL(k_border, dim3(520),  dim3(256), 0, stream, xs);
  hipLaunchKernelGGL(k_xpose,  dim3(512),  dim3(256), 0, stream, x, s, xs);
  hipLaunchKernelGGL(k_conv8,  dim3(256),  dim3(512), 65536, stream, wt, xs, dm, out);
}